// Round 6
// baseline (600.750 us; speedup 1.0000x reference)
//
#include <hip/hip_runtime.h>
#include <hip/hip_bf16.h>

typedef unsigned short ushort_t;
typedef unsigned int uint_t;

#define KL 1024
#define IL 8192
#define DIMV 128
#define NS 16
#define NB 258               // 32-col blocks per strip (258*32 = 8256 skewed steps)
#define NIT2 304             // wave15 finishes block 257 at i=302; even count
#define SSH (8256*64)        // ushorts per strip of c_h (fp16, pair-packed)
#define INF __builtin_inff()

typedef __attribute__((ext_vector_type(8))) short v8s;   // bf16x8 MFMA A/B frag
typedef __attribute__((ext_vector_type(4))) float v4f;   // MFMA C/D frag

// ---------------- kernel 1: squared row norms ----------------
__global__ __launch_bounds__(256) void knorms(
    const float* __restrict__ kern, const float* __restrict__ xx,
    float* __restrict__ x2, float* __restrict__ k2) {
  const int lane = threadIdx.x & 63;
  const int row = blockIdx.x * 4 + (threadIdx.x >> 6);
  const float* src;
  float* dst;
  if (row < IL) { src = xx + (size_t)row * DIMV; dst = x2 + row; }
  else          { src = kern + (size_t)(row - IL) * DIMV; dst = k2 + (row - IL); }
  float2 v = *(const float2*)(src + lane * 2);
  float ss = v.x * v.x + v.y * v.y;
  #pragma unroll
  for (int off = 32; off > 0; off >>= 1) ss += __shfl_down(ss, off, 64);
  if (lane == 0) *dst = ss;
}

// ---------------- kernel 2: MFMA bf16 GEMM -> c (fp16), lane-major block layout ----
// Layout: strip s, block b (32 cols), uint index = b*1024 + lane*16 + tpl
// where lane = row-within-strip (dk), tpl = (t>>1)&15, fp16 pair select = t&1.
// Each kdp lane then reads its 16 uints for a block as 64 contiguous bytes.
__device__ __forceinline__ v8s pack_bf16x8(float4 a, float4 b) {
  union { unsigned int u[4]; v8s v; } r;
  union { __hip_bfloat162 h; unsigned int u; } t;
  t.h = __float22bfloat162_rn(make_float2(a.x, a.y)); r.u[0] = t.u;
  t.h = __float22bfloat162_rn(make_float2(a.z, a.w)); r.u[1] = t.u;
  t.h = __float22bfloat162_rn(make_float2(b.x, b.y)); r.u[2] = t.u;
  t.h = __float22bfloat162_rn(make_float2(b.z, b.w)); r.u[3] = t.u;
  return r.v;
}

__global__ __launch_bounds__(256) void kgemm(
    const float* __restrict__ kern, const float* __restrict__ xx,
    const float* __restrict__ x2, const float* __restrict__ k2,
    ushort_t* __restrict__ c_h) {
  __shared__ float ctile[64 * 64];   // [n=x-col][m-swizzled]
  const int T = threadIdx.x;
  const int w = T >> 6;
  const int lane = T & 63;
  const int lo = lane & 15;
  const int hi = lane >> 4;
  const int i0 = blockIdx.x * 64;    // DTW columns (x rows)
  const int s  = blockIdx.y;         // strip
  const int kr0 = s * 64;

  v4f acc[4] = {};
  #pragma unroll
  for (int ks = 0; ks < 4; ks++) {
    const int k = ks * 32 + hi * 8;
    const float* bp = xx + (size_t)(i0 + w * 16 + lo) * DIMV + k;
    v8s bf = pack_bf16x8(*(const float4*)bp, *(const float4*)(bp + 4));
    #pragma unroll
    for (int rt = 0; rt < 4; rt++) {
      const float* ap = kern + (size_t)(kr0 + rt * 16 + lo) * DIMV + k;
      v8s af = pack_bf16x8(*(const float4*)ap, *(const float4*)(ap + 4));
      acc[rt] = __builtin_amdgcn_mfma_f32_16x16x32_bf16(af, bf, acc[rt], 0, 0, 0);
    }
  }
  const float x2v = x2[i0 + w * 16 + lo];
  const int n_local = w * 16 + lo;
  #pragma unroll
  for (int rt = 0; rt < 4; rt++) {
    float4 k2f = *(const float4*)&k2[kr0 + rt * 16 + hi * 4];
    #pragma unroll
    for (int q = 0; q < 4; q++) {
      const int m_local = rt * 16 + hi * 4 + q;
      float cval = fmaxf((&k2f.x)[q] + x2v - 2.f * acc[rt][q], 0.f);
      ctile[n_local * 64 + ((m_local + 2 * n_local) & 63)] = cval;
    }
  }
  __syncthreads();
  // skew-scatter as fp16 pairs: element (t = i0+tt, lane=dk), lane-major layout
  _Float16* ob = (_Float16*)(c_h + (size_t)s * SSH);
  #pragma unroll
  for (int q = 0; q < 32; q++) {
    int tt = w + q * 4;              // local skewed row in [0,126]
    int di = tt - lane;
    if (tt <= 126 && di >= 0 && di < 64) {
      int t = i0 + tt;
      int tp = t >> 1;
      ob[(((size_t)(tp >> 4) * 1024) + lane * 16 + (tp & 15)) * 2 + (t & 1)] =
          (_Float16)ctile[di * 64 + ((lane + 2 * di) & 63)];
    }
  }
}

// ---------------- kernel 3: SINGLE workgroup, 16 DP waves, lag-3 LDS ring ----------------
// All 16 strips in one wg: every strip boundary is the verified intra-wg LDS ring
// (wave k reads wave k-1's slot (W&3); producer writes slots W+1/W+2 that iter —
// disjoint mod 4). No sync wave, no bound/flags/atomics, no GATE, no cross-wg anything.
// DP body identical to the R5-verified one; wave0's boundary is constant INF
// (identical to wg0's permanently-INF feed in the 4-wg design).
__device__ __forceinline__ float dpp_wave_shr1(float oldv, float src) {
  return __int_as_float(__builtin_amdgcn_update_dpp(
      __float_as_int(oldv), __float_as_int(src), 0x138, 0xF, 0xF, false));
}

__global__ __launch_bounds__(1024, 4) void kdp(
    const ushort_t* __restrict__ c_h, float* __restrict__ out) {
  __shared__ __align__(16) float ring[16 * 4 * 32];  // wave k out-ring: ring + k*128
  const int wv = threadIdx.x >> 6;        // 0..15, all DP
  const int lane = threadIdx.x & 63;

  float Dcur = INF, Dul = INF;
  if (wv == 0 && lane == 0) Dcur = 0.f;

  // per-wave global base for its strip (lane-major layout)
  const uint_t* cbase = (const uint_t*)c_h + (size_t)wv * (SSH / 2) + lane * 16;

  uint_t P[16], Q[16];

  // preload block 0 into P (in-loop clamped prefetch re-stages block 0 for late waves)
  {
    const uint4* sp = (const uint4*)cbase;
    *(uint4*)&P[0] = sp[0]; *(uint4*)&P[4] = sp[1];
    *(uint4*)&P[8] = sp[2]; *(uint4*)&P[12] = sp[3];
  }
  __syncthreads();

  auto body = [&](int i, uint_t (&cur)[16], uint_t (&nxt)[16]) {
    // ---- DP wave k = wv, strip wv, block W = i - 3k (lag 3) ----
    const int W = i - 3 * wv;
    // depth-1 prefetch of block W+1 (clamped; always 4 loads, used NEXT iter)
    int Wn = W + 1; Wn = Wn < 0 ? 0 : (Wn > NB - 1 ? NB - 1 : Wn);
    {
      const uint4* sp = (const uint4*)(cbase + (size_t)Wn * 1024);
      *(uint4*)&nxt[0]  = sp[0]; *(uint4*)&nxt[4]  = sp[1];
      *(uint4*)&nxt[8]  = sp[2]; *(uint4*)&nxt[12] = sp[3];
    }
    if (W >= 0 && W < NB) {
      // boundary values for cols 32W+tt: wave0 = INF (top border), else ring of wave k-1
      float fv[32];
      if (wv == 0) {
        #pragma unroll
        for (int tt = 0; tt < 32; tt++) fv[tt] = INF;
      } else {
        const float* fb = &ring[(wv - 1) * 128 + (W & 3) * 32];
        #pragma unroll
        for (int q = 0; q < 8; q++) {
          float4 f4 = *(const float4*)(fb + q * 4);
          fv[4 * q]     = f4.x; fv[4 * q + 1] = f4.y;
          fv[4 * q + 2] = f4.z; fv[4 * q + 3] = f4.w;
        }
      }
      float cvv[32];
      #pragma unroll
      for (int tp = 0; tp < 16; tp++) {
        union { uint_t u; _Float16 h[2]; } cu; cu.u = cur[tp];
        cvv[2 * tp]     = (float)cu.h[0];
        cvv[2 * tp + 1] = (float)cu.h[1];
      }
      float bb[32];                       // lane63's per-step Dcur (SSA aliases)
      if (W >= 2 && W < 256) {
        #pragma unroll
        for (int tt = 0; tt < 32; tt++) {
          float Dup = dpp_wave_shr1(fv[tt], Dcur);  // lane0 hole <- boundary col 32W+tt
          float m1 = fminf(Dul, Dcur);              // parallel with dpp
          Dcur = cvv[tt] + fminf(m1, Dup);
          Dul = Dup;
          bb[tt] = Dcur;
        }
      } else {
        const int t0 = W * 32;
        #pragma unroll
        for (int tt = 0; tt < 32; tt++) {
          const int t = t0 + tt;
          float Dup = dpp_wave_shr1(fv[tt], Dcur);
          float m1 = fminf(Dul, Dcur);
          float Dnew = cvv[tt] + fminf(m1, Dup);
          const bool alo = (t >= lane);          // j >= 0
          const bool ahi = (t - lane < IL);      // j < IL
          if (alo) Dul = Dup;
          if (alo && ahi) Dcur = Dnew;
          bb[tt] = Dcur;
        }
      }
      // ring write: lane63's bottom-row values (verified mapping:
      // step tt -> col 32(W-2)+tt+1 -> slot W-2 pos tt+1 (tt<=30, W>=2);
      // tt=31 -> slot W-1 pos 0 (W>=1))
      if (lane == 63) {
        const int base2 = wv * 128 + (((W - 2) & 3) << 5);
        const int base1 = wv * 128 + (((W - 1) & 3) << 5);
        if (W >= 2) {
          #pragma unroll
          for (int tt = 0; tt < 31; tt++) ring[base2 + tt + 1] = bb[tt];
        }
        if (W >= 1) ring[base1] = bb[31];
      }
    }
    asm volatile("s_waitcnt lgkmcnt(0)" ::: "memory");  // ring writes visible
    __builtin_amdgcn_s_barrier();
  };

  for (int i = 0; i < NIT2; i += 2) {
    body(i, P, Q);
    body(i + 1, Q, P);
  }

  asm volatile("s_waitcnt vmcnt(0)" ::: "memory");  // quiesce in-flight prefetch
  if (wv == 15 && lane == 63) out[0] = Dcur;  // D[K-1][I-1] == optimal path sum
}

extern "C" void kernel_launch(void* const* d_in, const int* in_sizes, int n_in,
                              void* d_out, int out_size, void* d_ws, size_t ws_size,
                              hipStream_t stream) {
  const float* kern = (const float*)d_in[0]; // (1024,128)
  const float* xx   = (const float*)d_in[1]; // (8192,128)
  char* ws = (char*)d_ws;
  const size_t OFF_X2 = (size_t)NS * SSH * 2;           // c_h: ~16.9 MB
  const size_t OFF_K2 = OFF_X2 + (size_t)IL * 4;
  ushort_t* c_h  = (ushort_t*)ws;
  float* x2    = (float*)(ws + OFF_X2);
  float* k2    = (float*)(ws + OFF_K2);

  knorms<<<(IL + KL) / 4, 256, 0, stream>>>(kern, xx, x2, k2);
  kgemm<<<dim3(IL / 64, NS), 256, 0, stream>>>(kern, xx, x2, k2, c_h);
  kdp<<<1, 1024, 0, stream>>>(c_h, (float*)d_out);
}